// Round 1
// baseline (362.773 us; speedup 1.0000x reference)
//
#include <hip/hip_runtime.h>
#include <math.h>

// Problem constants (B,S,H,D,P fixed by the reference).
#define B_ 16
#define S_ 512
#define H_ 12
#define D_ 768
#define P_ 256
#define K_ 51
#define CH_ 16            // s-rows per k2 chunk
#define NCHUNK_ (S_/CH_)  // 32

// Monotonic float->uint key: larger float <=> larger unsigned.
__device__ __forceinline__ unsigned okey(float f) {
  unsigned u = __float_as_uint(f);
  return (u & 0x80000000u) ? ~u : (u | 0x80000000u);
}

// One block per (b,t) attention row: head-average, top-K select, scatter 1/cnt.
__global__ __launch_bounds__(256) void k1_topk_weights(
    const float* __restrict__ attn, float* __restrict__ w) {
  const int bt = blockIdx.x;
  const int b = bt >> 9;            // S_ == 512
  const int t = bt & (S_ - 1);
  const int tid = threadIdx.x;

  __shared__ unsigned keys[S_];
  __shared__ unsigned hist[256];
  __shared__ unsigned sbuf[256];
  __shared__ int ipar[4];  // [0]=pos count, [1]=chosen digit, [2]=count above, [3]=tie count

  // --- head-average: each thread owns elements 2*tid, 2*tid+1 ---
  const float* base = attn + (((size_t)b * H_) * S_ + t) * S_;
  float2 acc = make_float2(0.f, 0.f);
  #pragma unroll
  for (int h = 0; h < H_; ++h) {
    const float2 v = *(const float2*)(base + (size_t)h * S_ * S_ + 2 * tid);
    acc.x += v.x; acc.y += v.y;
  }
  const float a0 = acc.x * (1.0f / (float)H_);
  const float a1 = acc.y * (1.0f / (float)H_);
  const unsigned k0 = okey(a0);
  const unsigned k1v = okey(a1);
  keys[2 * tid] = k0;
  keys[2 * tid + 1] = k1v;

  // --- count strict positives in the row ---
  if (tid == 0) ipar[0] = 0;
  __syncthreads();
  {
    const int myPos = (a0 > 0.f) + (a1 > 0.f);
    if (myPos) atomicAdd(&ipar[0], myPos);
  }
  __syncthreads();
  const int p = ipar[0];

  bool sel0, sel1;
  float invcnt;
  if (p >= 1 && p < K_) {
    // kept set == all positive entries (they are all inside the top-K)
    sel0 = (a0 > 0.f);
    sel1 = (a1 > 0.f);
    invcnt = 1.0f / (float)p;
  } else {
    // p >= K (all top-K positive, keep K) or p == 0 (keep forced true, keep K):
    // exact top-K via 8-bit radix select on keys, jax tie-break (lowest index).
    unsigned prefix = 0;
    int remaining = K_;
    #pragma unroll
    for (int pass = 0; pass < 4; ++pass) {
      const int shift = 24 - 8 * pass;
      const unsigned pm = (pass == 0) ? 0u : (0xFFFFFFFFu << (shift + 8));
      hist[tid] = 0;
      __syncthreads();
      if ((k0 & pm) == prefix) atomicAdd(&hist[(k0 >> shift) & 255u], 1u);
      if ((k1v & pm) == prefix) atomicAdd(&hist[(k1v >> shift) & 255u], 1u);
      __syncthreads();
      // suffix-sum the 256-bin histogram with a single wave (no barriers inside)
      if (tid < 64) {
        const int lane = tid;
        const unsigned c0 = hist[4 * lane + 0];
        const unsigned c1 = hist[4 * lane + 1];
        const unsigned c2 = hist[4 * lane + 2];
        const unsigned c3 = hist[4 * lane + 3];
        const unsigned loc = c0 + c1 + c2 + c3;
        unsigned suf = loc;
        #pragma unroll
        for (int off = 1; off < 64; off <<= 1) {
          const unsigned v = __shfl_down(suf, off, 64);
          if (lane + off < 64) suf += v;
        }
        const unsigned after = suf - loc;  // sum over lanes > lane
        sbuf[4 * lane + 3] = after + c3;
        sbuf[4 * lane + 2] = after + c3 + c2;
        sbuf[4 * lane + 1] = after + c3 + c2 + c1;
        sbuf[4 * lane + 0] = after + c3 + c2 + c1 + c0;
      }
      __syncthreads();
      // pick the bucket where the cumulative-from-top crosses `remaining`
      const unsigned sd = sbuf[tid];
      const unsigned sd1 = (tid < 255) ? sbuf[tid + 1] : 0u;
      if (sd >= (unsigned)remaining && sd1 < (unsigned)remaining) {
        ipar[1] = tid;
        ipar[2] = (int)sd1;        // count strictly above chosen bucket
        ipar[3] = (int)(sd - sd1); // count inside chosen bucket (ties)
      }
      __syncthreads();
      prefix |= ((unsigned)ipar[1]) << shift;
      remaining -= ipar[2];
      // (next pass's writes are separated from these reads by its own barriers)
    }
    const unsigned T = prefix;     // key of the K-th largest element
    const int tieCnt = ipar[3];    // how many keys equal T
    sel0 = (k0 > T);
    sel1 = (k1v > T);
    if (tieCnt == remaining) {
      // common case: every tied element is kept (usually tieCnt == 1)
      sel0 |= (k0 == T);
      sel1 |= (k1v == T);
    } else {
      // rare exact-tie case: keep the `remaining` lowest-index ties (jax order)
      if (k0 == T) {
        int r = 0;
        for (int s2 = 0; s2 < 2 * tid; ++s2) r += (keys[s2] == T);
        if (r < remaining) sel0 = true;
      }
      if (k1v == T) {
        int r = 0;
        for (int s2 = 0; s2 < 2 * tid + 1; ++s2) r += (keys[s2] == T);
        if (r < remaining) sel1 = true;
      }
    }
    invcnt = 1.0f / (float)K_;
  }

  float* wrow = w + b * S_;
  if (sel0) atomicAdd(&wrow[2 * tid], invcnt);
  if (sel1) atomicAdd(&wrow[2 * tid + 1], invcnt);
}

// x[b,d] = sum_s coef[b,s] * hidden[b,s,d],  coef = (eta + (1-eta)*w)/S
__global__ __launch_bounds__(192) void k2_weighted_sum(
    const float* __restrict__ hidden, const float* __restrict__ w,
    const float* __restrict__ node_eta, float* __restrict__ x) {
  const int chunk = blockIdx.x;
  const int b = blockIdx.y;
  const int tid = threadIdx.x;  // 0..191 -> d = 4*tid .. 4*tid+3 (D_ = 768)
  __shared__ float coef[CH_];
  if (tid < CH_) {
    const float eta = node_eta[0];
    const float wv = w[b * S_ + chunk * CH_ + tid];
    coef[tid] = (eta + (1.0f - eta) * wv) * (1.0f / (float)S_);
  }
  __syncthreads();
  const float* hb = hidden + ((size_t)b * S_ + (size_t)chunk * CH_) * D_ + 4 * tid;
  float4 acc = make_float4(0.f, 0.f, 0.f, 0.f);
  #pragma unroll
  for (int s = 0; s < CH_; ++s) {
    const float4 v = *(const float4*)(hb + (size_t)s * D_);
    const float c = coef[s];
    acc.x += c * v.x; acc.y += c * v.y; acc.z += c * v.z; acc.w += c * v.w;
  }
  float* xp = x + b * D_ + 4 * tid;
  atomicAdd(xp + 0, acc.x);
  atomicAdd(xp + 1, acc.y);
  atomicAdd(xp + 2, acc.z);
  atomicAdd(xp + 3, acc.w);
}

// vec = x@W_node + b_node; t=tanh(vec); o = t@W_fc + b_fc; LayerNorm(o)
__global__ __launch_bounds__(256) void k3_final(
    const float* __restrict__ x, const float* __restrict__ W_node,
    const float* __restrict__ b_node, const float* __restrict__ W_fc,
    const float* __restrict__ b_fc, const float* __restrict__ gamma,
    const float* __restrict__ beta, float* __restrict__ out) {
  const int b = blockIdx.x;
  const int tid = threadIdx.x;  // == output channel p
  __shared__ float xs[D_];
  __shared__ float ts[P_];
  __shared__ float red[4];

  for (int d = tid; d < D_; d += 256) xs[d] = x[b * D_ + d];
  __syncthreads();

  float v = b_node[tid];
  for (int d = 0; d < D_; ++d) v += xs[d] * W_node[d * P_ + tid];
  ts[tid] = tanhf(v);
  __syncthreads();

  float o = b_fc[tid];
  for (int q = 0; q < P_; ++q) o += ts[q] * W_fc[q * P_ + tid];

  // block mean
  float s = o;
  #pragma unroll
  for (int off = 32; off > 0; off >>= 1) s += __shfl_down(s, off, 64);
  const int wave = tid >> 6, lane = tid & 63;
  if (lane == 0) red[wave] = s;
  __syncthreads();
  const float mu = (red[0] + red[1] + red[2] + red[3]) * (1.0f / (float)P_);
  __syncthreads();
  // block variance (two-pass, matches reference)
  const float dv = o - mu;
  float s2 = dv * dv;
  #pragma unroll
  for (int off = 32; off > 0; off >>= 1) s2 += __shfl_down(s2, off, 64);
  if (lane == 0) red[wave] = s2;
  __syncthreads();
  const float var = (red[0] + red[1] + red[2] + red[3]) * (1.0f / (float)P_);
  const float inv = 1.0f / sqrtf(var + 1e-5f);
  out[b * P_ + tid] = dv * inv * gamma[tid] + beta[tid];
}

extern "C" void kernel_launch(void* const* d_in, const int* in_sizes, int n_in,
                              void* d_out, int out_size, void* d_ws, size_t ws_size,
                              hipStream_t stream) {
  (void)in_sizes; (void)n_in; (void)out_size; (void)ws_size;
  const float* hidden   = (const float*)d_in[0];  // [B,S,D]
  const float* attn     = (const float*)d_in[1];  // [B,H,S,S]
  /* d_in[2] = length (== S, unused) */
  const float* W_node   = (const float*)d_in[3];  // [D,P]
  const float* b_node   = (const float*)d_in[4];  // [P]
  const float* node_eta = (const float*)d_in[5];  // [1]
  const float* W_fc     = (const float*)d_in[6];  // [P,P]
  const float* b_fc     = (const float*)d_in[7];  // [P]
  const float* gamma    = (const float*)d_in[8];  // [P]
  const float* beta     = (const float*)d_in[9];  // [P]
  float* out = (float*)d_out;                     // [B,P] fp32

  float* w = (float*)d_ws;        // B_*S_ floats (edge-weight sums per source node)
  float* x = w + B_ * S_;         // B_*D_ floats (coef-weighted hidden sums)
  hipMemsetAsync(d_ws, 0, (size_t)(B_ * S_ + B_ * D_) * sizeof(float), stream);

  k1_topk_weights<<<B_ * S_, 256, 0, stream>>>(attn, w);
  k2_weighted_sum<<<dim3(NCHUNK_, B_), 192, 0, stream>>>(hidden, w, node_eta, x);
  k3_final<<<B_, 256, 0, stream>>>(x, W_node, b_node, W_fc, b_fc, gamma, beta, out);
}